// Round 3
// baseline (765.971 us; speedup 1.0000x reference)
//
#include <hip/hip_runtime.h>

// ViT self-attention fwd on MI355X (gfx950).
// B=32, S=577, D=768, H=12, d=64. fp32 in/out; bf16 MFMA internally.
//
// Pipeline:
//   1) qkv_proj_kernel: X[18464,768] @ W^T (+bias) for q,k,v -> bf16 [B,H,S,64] in ws.
//      Q is pre-scaled by 1/sqrt(64)=0.125 (exact in bf16).
//   2) attn_kernel: per (b,h, 32-row q-tile): QK^T -> LDS fp32 scores ->
//      row softmax (unnormalized bf16 probs in LDS) -> PV MFMA -> scale by 1/sum -> out.

#define SEQ 577
#define DMODEL 768
#define NHEADS 12
#define HDIM 64
#define MTOTAL (32 * SEQ) /* 18464 rows = B*S */

typedef __attribute__((ext_vector_type(8))) short bf16x8;
typedef __attribute__((ext_vector_type(4))) float f32x4;

#define MFMA_BF16(a, b, c) __builtin_amdgcn_mfma_f32_16x16x32_bf16((a), (b), (c), 0, 0, 0)

// fp32 -> bf16 round-to-nearest-even
static __device__ __forceinline__ unsigned short f2bf(float x) {
    unsigned int u = __float_as_uint(x);
    unsigned int r = (u + 0x7FFFu + ((u >> 16) & 1u)) >> 16;
    return (unsigned short)r;
}

// convert 8 consecutive fp32 -> 8 bf16, store as one 16B chunk
static __device__ __forceinline__ void cvt8(unsigned short* dst, const float* src) {
    float4 a = *reinterpret_cast<const float4*>(src);
    float4 b = *reinterpret_cast<const float4*>(src + 4);
    union { unsigned short us[8]; int4 v; } u;
    u.us[0] = f2bf(a.x); u.us[1] = f2bf(a.y); u.us[2] = f2bf(a.z); u.us[3] = f2bf(a.w);
    u.us[4] = f2bf(b.x); u.us[5] = f2bf(b.y); u.us[6] = f2bf(b.z); u.us[7] = f2bf(b.w);
    *reinterpret_cast<int4*>(dst) = u.v;
}

// ---------------------------------------------------------------------------
// QKV projection: C[m,n] = X[m,:] . W[n,:] + b[n]   (nn.Linear: x @ W.T + b)
// 64x64 tile per block, 4 waves (each wave: 16 rows x 64 cols), BK=64.
// LDS rows padded to 72 bf16 (144B) -> 2-way bank aliasing only (free).
// ---------------------------------------------------------------------------
__global__ __launch_bounds__(256) void qkv_proj_kernel(
    const float* __restrict__ X,
    const float* __restrict__ Wq, const float* __restrict__ bq,
    const float* __restrict__ Wk, const float* __restrict__ bk,
    const float* __restrict__ Wv, const float* __restrict__ bv,
    unsigned short* __restrict__ Qb, unsigned short* __restrict__ Kb,
    unsigned short* __restrict__ Vb)
{
    const int z = blockIdx.z;
    const float* W    = (z == 0) ? Wq : ((z == 1) ? Wk : Wv);
    const float* bias = (z == 0) ? bq : ((z == 1) ? bk : bv);
    unsigned short* Out = (z == 0) ? Qb : ((z == 1) ? Kb : Vb);
    const float outscale = (z == 0) ? 0.125f : 1.0f; // fold 1/sqrt(d) into Q (exact)

    const int m0 = blockIdx.x * 64;
    const int n0 = blockIdx.y * 64;
    const int t = (int)threadIdx.x;
    const int lane = t & 63;
    const int wid = t >> 6;

    __shared__ __align__(16) unsigned short Xs[64][72];
    __shared__ __align__(16) unsigned short Ws[64][72];

    const f32x4 zero = {0.f, 0.f, 0.f, 0.f};
    f32x4 acc[4] = {zero, zero, zero, zero};

    // staging assignment: 4 threads per row, 16 fp32 each
    const int lrow = t >> 2;
    const int lcol = (t & 3) * 16;
    int xr = m0 + lrow; if (xr > MTOTAL - 1) xr = MTOTAL - 1; // clamp OOB rows (stores guarded)
    const float* xp = X + (size_t)xr * DMODEL + lcol;
    const float* wp = W + (size_t)(n0 + lrow) * DMODEL + lcol;

    for (int k0 = 0; k0 < DMODEL; k0 += 64) {
        cvt8(&Xs[lrow][lcol],     xp + k0);
        cvt8(&Xs[lrow][lcol + 8], xp + k0 + 8);
        cvt8(&Ws[lrow][lcol],     wp + k0);
        cvt8(&Ws[lrow][lcol + 8], wp + k0 + 8);
        __syncthreads();
        #pragma unroll
        for (int ks = 0; ks < 2; ++ks) {
            bf16x8 a = *reinterpret_cast<const bf16x8*>(
                &Xs[wid * 16 + (lane & 15)][ks * 32 + (lane >> 4) * 8]);
            #pragma unroll
            for (int nf = 0; nf < 4; ++nf) {
                bf16x8 w8 = *reinterpret_cast<const bf16x8*>(
                    &Ws[nf * 16 + (lane & 15)][ks * 32 + (lane >> 4) * 8]);
                acc[nf] = MFMA_BF16(a, w8, acc[nf]);
            }
        }
        __syncthreads();
    }

    // epilogue: D row = (lane>>4)*4 + r (verified C/D mapping), col = lane&15
    const int rb = wid * 16 + ((lane >> 4) << 2);
    #pragma unroll
    for (int nf = 0; nf < 4; ++nf) {
        const int n = n0 + nf * 16 + (lane & 15);
        const float bval = bias[n];
        const int h = n >> 6, dd = n & 63;
        #pragma unroll
        for (int r = 0; r < 4; ++r) {
            const int gm = m0 + rb + r;
            if (gm < MTOTAL) {
                const int bi = gm / SEQ, s = gm % SEQ;
                Out[(((size_t)bi * NHEADS + h) * SEQ + s) * HDIM + dd] =
                    f2bf((acc[nf][r] + bval) * outscale);
            }
        }
    }
}

// ---------------------------------------------------------------------------
// Fused attention: one block per (q-tile of 32 rows, b*h). 4 waves.
// LDS: Qs bf16[32][72] | rowinv f32[32] | Ss f32[32][592] | Ps bf16[32][608]
// total 119424 B (dynamic).
// ---------------------------------------------------------------------------
__global__ __launch_bounds__(256) void attn_kernel(
    const unsigned short* __restrict__ Qb,
    const unsigned short* __restrict__ Kb,
    const unsigned short* __restrict__ Vb,
    float* __restrict__ Out)
{
    extern __shared__ __align__(16) char smem[];
    unsigned short* Qs = (unsigned short*)smem;            // [32][72] bf16
    float* rowinv = (float*)(smem + 4608);                 // [32]
    float* Ss = (float*)(smem + 4736);                     // [32][592] fp32
    unsigned short* Ps = (unsigned short*)(smem + 80512);  // [32][608] bf16

    const int qt = blockIdx.x;   // 0..18
    const int bh = blockIdx.y;   // 0..383
    const int s0 = qt * 32;
    const int t = (int)threadIdx.x;
    const int lane = t & 63;
    const int wid = t >> 6;
    const size_t base = (size_t)bh * SEQ * HDIM;

    // --- load Q tile (already pre-scaled by 0.125); OOB rows -> 0
    {
        const int r = t >> 3, c = (t & 7) * 8;
        const int s = s0 + r;
        int4 v = {0, 0, 0, 0};
        if (s < SEQ) v = *reinterpret_cast<const int4*>(Qb + base + (size_t)s * HDIM + c);
        *reinterpret_cast<int4*>(&Qs[r * 72 + c]) = v;
    }
    __syncthreads();

    // --- QK^T: scores[32][592] (keys padded/clamped past 577; masked in softmax)
    bf16x8 afr[2][2];
    #pragma unroll
    for (int mi = 0; mi < 2; ++mi)
        #pragma unroll
        for (int ks = 0; ks < 2; ++ks)
            afr[mi][ks] = *reinterpret_cast<const bf16x8*>(
                &Qs[(mi * 16 + (lane & 15)) * 72 + ks * 32 + (lane >> 4) * 8]);

    const f32x4 zero = {0.f, 0.f, 0.f, 0.f};
    for (int nf = wid; nf < 37; nf += 4) {
        int kr = nf * 16 + (lane & 15); if (kr > SEQ - 1) kr = SEQ - 1;
        const unsigned short* kp = Kb + base + (size_t)kr * HDIM + (lane >> 4) * 8;
        bf16x8 b0 = *reinterpret_cast<const bf16x8*>(kp);
        bf16x8 b1 = *reinterpret_cast<const bf16x8*>(kp + 32);
        f32x4 acc0 = zero, acc1 = zero;
        acc0 = MFMA_BF16(afr[0][0], b0, acc0);
        acc0 = MFMA_BF16(afr[0][1], b1, acc0);
        acc1 = MFMA_BF16(afr[1][0], b0, acc1);
        acc1 = MFMA_BF16(afr[1][1], b1, acc1);
        const int col = nf * 16 + (lane & 15);
        const int rbase = (lane >> 4) * 4;
        #pragma unroll
        for (int r = 0; r < 4; ++r) {
            Ss[(rbase + r) * 592 + col] = acc0[r];
            Ss[(rbase + r + 16) * 592 + col] = acc1[r];
        }
    }
    __syncthreads();

    // --- softmax per row: 8 threads/row; unnormalized p -> bf16 Ps; 1/sum saved
    {
        const int r = t >> 3, j = t & 7;
        const float* srow = Ss + r * 592;
        float mx = -1e30f;
        for (int c = j; c < SEQ; c += 8) mx = fmaxf(mx, srow[c]);
        mx = fmaxf(mx, __shfl_xor(mx, 1));
        mx = fmaxf(mx, __shfl_xor(mx, 2));
        mx = fmaxf(mx, __shfl_xor(mx, 4));
        unsigned short* prow = Ps + r * 608;
        float sum = 0.f;
        for (int c = j; c < SEQ; c += 8) {
            float p = __expf(srow[c] - mx);
            unsigned short us = f2bf(p);
            prow[c] = us;
            sum += __uint_as_float((unsigned int)us << 16); // sum what PV will actually use
        }
        for (int c = SEQ + j; c < 608; c += 8) prow[c] = 0; // zero pad cols 577..607
        sum += __shfl_xor(sum, 1);
        sum += __shfl_xor(sum, 2);
        sum += __shfl_xor(sum, 4);
        if (j == 0) rowinv[r] = 1.0f / sum;
    }
    __syncthreads();

    // --- PV: each wave owns 16 output cols (dd = wid*16 + lane&15)
    f32x4 o0 = zero, o1 = zero;
    const int dd = wid * 16 + (lane & 15);
    const unsigned short* Vp = Vb + base + dd;
    for (int k0 = 0; k0 < 608; k0 += 32) {
        const int vrb = k0 + (lane >> 4) * 8;
        bf16x8 bfr;
        #pragma unroll
        for (int j = 0; j < 8; ++j) {
            int vr = vrb + j; if (vr > SEQ - 1) vr = SEQ - 1; // P=0 past 576 -> value irrelevant
            bfr[j] = (short)Vp[(size_t)vr * HDIM];
        }
        bf16x8 a0 = *reinterpret_cast<const bf16x8*>(&Ps[(lane & 15) * 608 + k0 + (lane >> 4) * 8]);
        bf16x8 a1 = *reinterpret_cast<const bf16x8*>(&Ps[(16 + (lane & 15)) * 608 + k0 + (lane >> 4) * 8]);
        o0 = MFMA_BF16(a0, bfr, o0);
        o1 = MFMA_BF16(a1, bfr, o1);
    }

    // --- store ctx, normalized; out layout [B,S,H*d] fp32
    const int bi = bh / NHEADS, h = bh % NHEADS;
    const int rbase = (lane >> 4) * 4;
    #pragma unroll
    for (int r = 0; r < 4; ++r) {
        {
            const int row = rbase + r;
            const int s = s0 + row;
            if (s < SEQ)
                Out[((size_t)bi * SEQ + s) * DMODEL + h * HDIM + dd] = o0[r] * rowinv[row];
        }
        {
            const int row = rbase + r + 16;
            const int s = s0 + row;
            if (s < SEQ)
                Out[((size_t)bi * SEQ + s) * DMODEL + h * HDIM + dd] = o1[r] * rowinv[row];
        }
    }
}

extern "C" void kernel_launch(void* const* d_in, const int* in_sizes, int n_in,
                              void* d_out, int out_size, void* d_ws, size_t ws_size,
                              hipStream_t stream) {
    (void)in_sizes; (void)n_in; (void)out_size; (void)ws_size;
    const float* X  = (const float*)d_in[0];
    const float* Wq = (const float*)d_in[1];
    const float* bq = (const float*)d_in[2];
    const float* Wk = (const float*)d_in[3];
    const float* bk = (const float*)d_in[4];
    const float* Wv = (const float*)d_in[5];
    const float* bv = (const float*)d_in[6];
    float* Out = (float*)d_out;

    // ws: Q,K,V bf16, each 18464*768 elems = 28,360,704 B; total ~85 MB
    const size_t per = (size_t)MTOTAL * DMODEL;
    unsigned short* Qb = (unsigned short*)d_ws;
    unsigned short* Kb = Qb + per;
    unsigned short* Vb = Kb + per;

    // allow >64KB dynamic LDS (gfx950 has 160KB/CU); harmless if already set
    hipFuncSetAttribute((const void*)attn_kernel,
                        hipFuncAttributeMaxDynamicSharedMemorySize, 119424);

    dim3 g1((MTOTAL + 63) / 64, DMODEL / 64, 3);
    qkv_proj_kernel<<<g1, 256, 0, stream>>>(X, Wq, bq, Wk, bk, Wv, bv, Qb, Kb, Vb);

    dim3 g2((SEQ + 31) / 32, 32 * NHEADS);
    attn_kernel<<<g2, 256, 119424, stream>>>(Qb, Kb, Vb, Out);
}

// Round 6
// 426.547 us; speedup vs baseline: 1.7957x; 1.7957x over previous
//
#include <hip/hip_runtime.h>

// ViT self-attention fwd on MI355X (gfx950).
// B=32, S=577, D=768, H=12, d=64. fp32 in/out; bf16 MFMA internally.
//
// Pipeline:
//  (FAST, ws >= ~113MiB)
//   0) conv_kernel: X fp32 -> Xb bf16, W{q,k,v} -> Wb bf16.
//   1) gemm_qkv<true>: 128x128xBK64, global_load_lds(16B) staging -> Qb, Kb (bf16
//      [bh][s][64]) and Vt (bf16 [bh][64][608], d-major for PV B-frags).
//  (SLOW fallback) gemm_qkv<false>: reg-staged fp32->bf16 cvt, Vt stride 584.
//   2) attn2: per (32-q-tile, bh): swapped QK^T (D[key][q]) -> packed-bf16 score
//      rows in LDS (39.5KB -> 4 blocks/CU; stride 1232B = 20 banks mod 32 ->
//      naturally balanced, NO swizzle) -> vectorized softmax (unnormalized bf16
//      P in place) -> PV MFMA (V from Vt) -> *1/sum -> out.

#define SEQ 577
#define DMODEL 768
#define NHEADS 12
#define HDIM 64
#define MTOTAL (32 * 577)      /* 18464 */
#define MPAD 18560             /* 145*128 */
#define KP 608                 /* padded key count (19 chunks of 32) */
#define STW 616                /* St row stride in shorts; 1232 B = 77 chunks */

typedef __attribute__((ext_vector_type(8))) short bf16x8;
typedef __attribute__((ext_vector_type(4))) float f32x4;

#define MFMA_BF16(a, b, c) __builtin_amdgcn_mfma_f32_16x16x32_bf16((a), (b), (c), 0, 0, 0)

static __device__ __forceinline__ unsigned short f2bf(float x) {
    unsigned int u = __float_as_uint(x);
    return (unsigned short)((u + 0x7FFFu + ((u >> 16) & 1u)) >> 16);
}
static __device__ __forceinline__ float bf2f(unsigned short s) {
    return __uint_as_float((unsigned int)s << 16);
}
static __device__ __forceinline__ void cvt8(unsigned short* dst, const float* src) {
    float4 a = *reinterpret_cast<const float4*>(src);
    float4 b = *reinterpret_cast<const float4*>(src + 4);
    union { unsigned short us[8]; int4 v; } u;
    u.us[0] = f2bf(a.x); u.us[1] = f2bf(a.y); u.us[2] = f2bf(a.z); u.us[3] = f2bf(a.w);
    u.us[4] = f2bf(b.x); u.us[5] = f2bf(b.y); u.us[6] = f2bf(b.z); u.us[7] = f2bf(b.w);
    *reinterpret_cast<int4*>(dst) = u.v;
}
static __device__ __forceinline__ void gload_lds16(const void* g, void* l) {
    __builtin_amdgcn_global_load_lds(
        (const __attribute__((address_space(1))) void*)g,
        (__attribute__((address_space(3))) void*)l, 16, 0, 0);
}

// ---------------------------------------------------------------------------
// fp32 -> bf16 convert pass (FAST path only): X and the three W matrices.
// ---------------------------------------------------------------------------
#define NX8 (MTOTAL * DMODEL / 8)   /* 1772544 */
#define NW8 (DMODEL * DMODEL / 8)   /* 73728 */
__global__ __launch_bounds__(256) void conv_kernel(
    const float* __restrict__ X, const float* __restrict__ Wq,
    const float* __restrict__ Wk, const float* __restrict__ Wv,
    unsigned short* __restrict__ Xb, unsigned short* __restrict__ Wb)
{
    const int total = NX8 + 3 * NW8;
    for (int i = blockIdx.x * blockDim.x + threadIdx.x; i < total;
         i += gridDim.x * blockDim.x) {
        if (i < NX8) {
            cvt8(Xb + (size_t)i * 8, X + (size_t)i * 8);
        } else {
            int j = i - NX8;
            int w = j / NW8, o = j - w * NW8;
            const float* Wf = (w == 0) ? Wq : ((w == 1) ? Wk : Wv);
            cvt8(Wb + (size_t)w * DMODEL * DMODEL + (size_t)o * 8, Wf + (size_t)o * 8);
        }
    }
}

// ---------------------------------------------------------------------------
// QKV GEMM: C[m,n] = X[m,:] . W[n,:] + b[n], 128x128 tile, 4 waves (2x2),
// BK=64. FAST: global_load_lds from bf16 Xb/Wb (linear LDS [128][64]).
// SLOW: reg-staged cvt from fp32 (padded LDS [128][72]).
// Outputs: z=0 -> Qb (*0.125), z=1 -> Kb, z=2 -> Vt (d-major, stride vstride).
// ---------------------------------------------------------------------------
template<bool FAST>
__global__ __launch_bounds__(256) void gemm_qkv(
    const float* __restrict__ X, const unsigned short* __restrict__ Xb,
    const float* __restrict__ Wq, const float* __restrict__ Wk,
    const float* __restrict__ Wv, const unsigned short* __restrict__ Wb,
    const float* __restrict__ bq, const float* __restrict__ bk,
    const float* __restrict__ bv,
    unsigned short* __restrict__ Qb, unsigned short* __restrict__ Kb,
    unsigned short* __restrict__ Vt, int vstride)
{
    constexpr int LDA = FAST ? 64 : 72;
    __shared__ __align__(16) unsigned short As[128 * LDA];
    __shared__ __align__(16) unsigned short Bs[128 * LDA];

    const int z = blockIdx.z;
    const float* bias = (z == 0) ? bq : ((z == 1) ? bk : bv);
    const float outscale = (z == 0) ? 0.125f : 1.0f;

    const int m0 = blockIdx.x * 128;
    const int n0 = blockIdx.y * 128;
    const int t = (int)threadIdx.x;
    const int lane = t & 63, wid = t >> 6;
    const int hi = lane >> 4, l15 = lane & 15;
    const int wr = wid >> 1, wc = wid & 1;

    const f32x4 zero = {0.f, 0.f, 0.f, 0.f};
    f32x4 acc[4][4];
    #pragma unroll
    for (int i = 0; i < 4; ++i)
        #pragma unroll
        for (int j = 0; j < 4; ++j) acc[i][j] = zero;

    // staging addressing
    const unsigned short* gA = nullptr; const unsigned short* gB = nullptr;
    const float* xp = nullptr; const float* wp = nullptr;
    if constexpr (FAST) {
        const int srow = wid * 8 + (lane >> 3);
        const int scol = (lane & 7) * 8;
        gA = Xb + (size_t)(m0 + srow) * DMODEL + scol;
        gB = Wb + (size_t)z * DMODEL * DMODEL + (size_t)(n0 + srow) * DMODEL + scol;
    } else {
        const int lrow = t >> 1, lcol = (t & 1) * 32;
        int xr = m0 + lrow; if (xr > MTOTAL - 1) xr = MTOTAL - 1;
        xp = X + (size_t)xr * DMODEL + lcol;
        const float* Wf = (z == 0) ? Wq : ((z == 1) ? Wk : Wv);
        wp = Wf + (size_t)(n0 + lrow) * DMODEL + lcol;
    }

    for (int k0 = 0; k0 < DMODEL; k0 += 64) {
        if constexpr (FAST) {
            #pragma unroll
            for (int c = 0; c < 4; ++c) {
                gload_lds16(gA + (size_t)c * 32 * DMODEL + k0, As + wid * 512 + c * 2048);
                gload_lds16(gB + (size_t)c * 32 * DMODEL + k0, Bs + wid * 512 + c * 2048);
            }
        } else {
            const int lrow = t >> 1, lcol = (t & 1) * 32;
            #pragma unroll
            for (int c = 0; c < 4; ++c) {
                cvt8(As + lrow * LDA + lcol + c * 8, xp + k0 + c * 8);
                cvt8(Bs + lrow * LDA + lcol + c * 8, wp + k0 + c * 8);
            }
        }
        __syncthreads();
        #pragma unroll
        for (int kc = 0; kc < 2; ++kc) {
            bf16x8 a[4], b[4];
            #pragma unroll
            for (int i = 0; i < 4; ++i)
                a[i] = *reinterpret_cast<const bf16x8*>(
                    As + (wr * 64 + i * 16 + l15) * LDA + kc * 32 + hi * 8);
            #pragma unroll
            for (int i = 0; i < 4; ++i)
                b[i] = *reinterpret_cast<const bf16x8*>(
                    Bs + (wc * 64 + i * 16 + l15) * LDA + kc * 32 + hi * 8);
            #pragma unroll
            for (int mf = 0; mf < 4; ++mf)
                #pragma unroll
                for (int nf = 0; nf < 4; ++nf)
                    acc[mf][nf] = MFMA_BF16(a[mf], b[nf], acc[mf][nf]);
        }
        __syncthreads();
    }

    // epilogue
    #pragma unroll
    for (int nf = 0; nf < 4; ++nf) {
        const int n = n0 + wc * 64 + nf * 16 + l15;
        const float bval = bias[n];
        const int h = n >> 6, dd = n & 63;
        #pragma unroll
        for (int mf = 0; mf < 4; ++mf) {
            #pragma unroll
            for (int r = 0; r < 4; ++r) {
                const int gm = m0 + wr * 64 + mf * 16 + hi * 4 + r;
                if (gm < MTOTAL) {
                    const int bi = gm / SEQ, s = gm - ((gm / SEQ) * SEQ);
                    const int bh = bi * NHEADS + h;
                    const unsigned short v = f2bf((acc[mf][nf][r] + bval) * outscale);
                    if (z == 2)
                        Vt[((size_t)bh * HDIM + dd) * vstride + s] = v;
                    else if (z == 0)
                        Qb[((size_t)bh * SEQ + s) * HDIM + dd] = v;
                    else
                        Kb[((size_t)bh * SEQ + s) * HDIM + dd] = v;
                }
            }
        }
    }
}

// ---------------------------------------------------------------------------
// Fused attention v2: block = (32 q-rows, bh), 4 waves, 39.6KB LDS -> 4 blk/CU.
// St[q][key] bf16, plain layout (stride 1232 B: bank-balanced by construction).
// ---------------------------------------------------------------------------
__global__ __launch_bounds__(256) void attn2(
    const unsigned short* __restrict__ Qb,
    const unsigned short* __restrict__ Kb,
    const unsigned short* __restrict__ Vt,
    float* __restrict__ Out, int vstride)
{
    __shared__ __align__(16) unsigned short St[32 * STW]; // 39424 B
    __shared__ float rowinv[32];

    const int qt = blockIdx.x, bh = blockIdx.y;
    const int s0 = qt * 32;
    const int t = (int)threadIdx.x;
    const int lane = t & 63, wid = t >> 6;
    const int hi = lane >> 4, l15 = lane & 15;
    const size_t base = (size_t)bh * SEQ * HDIM;
    const f32x4 zero = {0.f, 0.f, 0.f, 0.f};

    // --- Q B-frags from global (clamped rows)
    bf16x8 qf0[2], qf1[2];
    #pragma unroll
    for (int mb = 0; mb < 2; ++mb) {
        int qrow = s0 + mb * 16 + l15; if (qrow > SEQ - 1) qrow = SEQ - 1;
        const unsigned short* qp = Qb + base + (size_t)qrow * HDIM + hi * 8;
        qf0[mb] = *reinterpret_cast<const bf16x8*>(qp);
        qf1[mb] = *reinterpret_cast<const bf16x8*>(qp + 32);
    }

    // --- swapped QK^T: D[key][q]; store packed bf16 pairs into St[q][key]
    for (int kt = wid; kt < 37; kt += 4) {
        int kr = kt * 16 + l15; if (kr > SEQ - 1) kr = SEQ - 1;
        const unsigned short* kp = Kb + base + (size_t)kr * HDIM + hi * 8;
        bf16x8 a0 = *reinterpret_cast<const bf16x8*>(kp);
        bf16x8 a1 = *reinterpret_cast<const bf16x8*>(kp + 32);
        f32x4 acc0 = zero, acc1 = zero;
        acc0 = MFMA_BF16(a0, qf0[0], acc0);
        acc0 = MFMA_BF16(a1, qf1[0], acc0);
        acc1 = MFMA_BF16(a0, qf0[1], acc1);
        acc1 = MFMA_BF16(a1, qf1[1], acc1);
        const int obase = 32 * kt + 8 * hi; // byte offset of key kt*16+4*hi in row
        {
            char* rowp = (char*)St + l15 * (STW * 2);
            int2 w = {(int)((unsigned int)f2bf(acc0[0]) | ((unsigned int)f2bf(acc0[1]) << 16)),
                      (int)((unsigned int)f2bf(acc0[2]) | ((unsigned int)f2bf(acc0[3]) << 16))};
            *reinterpret_cast<int2*>(rowp + obase) = w;
        }
        {
            char* rowp = (char*)St + (16 + l15) * (STW * 2);
            int2 w = {(int)((unsigned int)f2bf(acc1[0]) | ((unsigned int)f2bf(acc1[1]) << 16)),
                      (int)((unsigned int)f2bf(acc1[2]) | ((unsigned int)f2bf(acc1[3]) << 16))};
            *reinterpret_cast<int2*>(rowp + obase) = w;
        }
    }
    __syncthreads();

    // --- softmax: 8 threads/row, vectorized b128; P (unnormalized bf16) in place
    {
        const int r = t >> 3, j = t & 7;
        char* rowp = (char*)St + r * (STW * 2);
        float mx = -1e30f;
        for (int cc = j; cc < 74; cc += 8) { // cols 0..591 (577+ dup of 576: max-safe)
            bf16x8 v = *reinterpret_cast<const bf16x8*>(rowp + cc * 16);
            #pragma unroll
            for (int e = 0; e < 8; ++e) mx = fmaxf(mx, bf2f((unsigned short)v[e]));
        }
        mx = fmaxf(mx, __shfl_xor(mx, 1));
        mx = fmaxf(mx, __shfl_xor(mx, 2));
        mx = fmaxf(mx, __shfl_xor(mx, 4));
        float sum = 0.f;
        for (int cc = j; cc < 74; cc += 8) {
            bf16x8 v = *reinterpret_cast<const bf16x8*>(rowp + cc * 16);
            unsigned int w[4];
            #pragma unroll
            for (int e = 0; e < 8; e += 2) {
                float p0 = __expf(bf2f((unsigned short)v[e]) - mx);
                float p1 = __expf(bf2f((unsigned short)v[e + 1]) - mx);
                if (cc * 8 + e     >= SEQ) p0 = 0.f;
                if (cc * 8 + e + 1 >= SEQ) p1 = 0.f;
                sum += p0 + p1;
                w[e >> 1] = (unsigned int)f2bf(p0) | ((unsigned int)f2bf(p1) << 16);
            }
            int4 wv = {(int)w[0], (int)w[1], (int)w[2], (int)w[3]};
            *reinterpret_cast<int4*>(rowp + cc * 16) = wv;
        }
        if (j < 2) { // zero chunks 74,75 (cols 592..607)
            int4 zv = {0, 0, 0, 0};
            *reinterpret_cast<int4*>(rowp + (74 + j) * 16) = zv;
        }
        sum += __shfl_xor(sum, 1);
        sum += __shfl_xor(sum, 2);
        sum += __shfl_xor(sum, 4);
        if (j == 0) rowinv[r] = 1.0f / sum;
    }
    __syncthreads();

    // --- PV: wave owns 16 dd cols; A = P rows (LDS), B = Vt (global, d-major)
    f32x4 o0 = zero, o1 = zero;
    const int dd = wid * 16 + l15;
    const unsigned short* vbase = Vt + ((size_t)bh * HDIM + dd) * vstride;
    for (int k0 = 0; k0 < KP; k0 += 32) {
        int vk = k0 + hi * 8;
        if (vk > 576) vk = 576; // cols >576 have P=0; clamp keeps loads in-bounds
        union { bf16x8 v8; int2 d2[2]; } u;
        u.d2[0] = *reinterpret_cast<const int2*>(vbase + vk);
        u.d2[1] = *reinterpret_cast<const int2*>(vbase + vk + 4);
        #pragma unroll
        for (int mb = 0; mb < 2; ++mb) {
            const int q = mb * 16 + l15;
            const char* pp = (const char*)St + q * (STW * 2) + 2 * k0 + 16 * hi;
            bf16x8 pa = *reinterpret_cast<const bf16x8*>(pp);
            if (mb == 0) o0 = MFMA_BF16(pa, u.v8, o0);
            else         o1 = MFMA_BF16(pa, u.v8, o1);
        }
    }

    // --- store
    const int bi = bh / NHEADS, h = bh - bi * NHEADS;
    #pragma unroll
    for (int r = 0; r < 4; ++r) {
        {
            const int q = hi * 4 + r, s = s0 + q;
            if (s < SEQ)
                Out[((size_t)bi * SEQ + s) * DMODEL + h * HDIM + dd] = o0[r] * rowinv[q];
        }
        {
            const int q = 16 + hi * 4 + r, s = s0 + q;
            if (s < SEQ)
                Out[((size_t)bi * SEQ + s) * DMODEL + h * HDIM + dd] = o1[r] * rowinv[q];
        }
    }
}

extern "C" void kernel_launch(void* const* d_in, const int* in_sizes, int n_in,
                              void* d_out, int out_size, void* d_ws, size_t ws_size,
                              hipStream_t stream) {
    (void)in_sizes; (void)n_in; (void)out_size;
    const float* X  = (const float*)d_in[0];
    const float* Wq = (const float*)d_in[1];
    const float* bq = (const float*)d_in[2];
    const float* Wk = (const float*)d_in[3];
    const float* bk = (const float*)d_in[4];
    const float* Wv = (const float*)d_in[5];
    const float* bv = (const float*)d_in[6];
    float* Out = (float*)d_out;

    const size_t E_QK = (size_t)MTOTAL * DMODEL;           // Q/K elems
    const size_t E_XB = (size_t)MPAD * DMODEL;
    const size_t E_WB = 3ull * DMODEL * DMODEL;
    const size_t E_VT_F = 384ull * HDIM * KP;              // fast Vt (stride 608)
    const size_t need_fast = (E_XB + E_WB + 2 * E_QK + E_VT_F) * 2;

    const bool fast = (ws_size >= need_fast);
    unsigned short* p = (unsigned short*)d_ws;
    unsigned short *Xb = nullptr, *Wb = nullptr, *Qb, *Kb, *Vt;
    int vstride;
    if (fast) {
        Xb = p; p += E_XB;
        Wb = p; p += E_WB;
        Qb = p; p += E_QK;
        Kb = p; p += E_QK;
        Vt = p;
        vstride = KP;
    } else {
        Qb = p; p += E_QK;
        Kb = p; p += E_QK;
        Vt = p;
        vstride = 584;
    }

    dim3 gg((MPAD) / 128, DMODEL / 128, 3);
    if (fast) {
        conv_kernel<<<2048, 256, 0, stream>>>(X, Wq, Wk, Wv, Xb, Wb);
        gemm_qkv<true><<<gg, 256, 0, stream>>>(X, Xb, Wq, Wk, Wv, Wb,
                                               bq, bk, bv, Qb, Kb, Vt, vstride);
    } else {
        gemm_qkv<false><<<gg, 256, 0, stream>>>(X, Xb, Wq, Wk, Wv, Wb,
                                                bq, bk, bv, Qb, Kb, Vt, vstride);
    }
    attn2<<<dim3((SEQ + 31) / 32, 32 * NHEADS), 256, 0, stream>>>(Qb, Kb, Vt, Out, vstride);
}

// Round 11
// 418.174 us; speedup vs baseline: 1.8317x; 1.0200x over previous
//
#include <hip/hip_runtime.h>

// ViT self-attention fwd on MI355X (gfx950).
// B=32, S=577, D=768, H=12, d=64. fp32 in/out; bf16 MFMA internally.
//
// Round 7:
//  gemm_qkv FAST: double-buffered LDS + raw s_barrier + counted vmcnt(8)
//    (8 gload_lds per wave per tile stay in flight across the barrier), plus
//    XOR bank-swizzle done both-sides (linear LDS dest for global_load_lds,
//    pre-swizzled GLOBAL source column, matching XOR on ds_read).
//  attn2: register prefetch for K and Vt loads; first Vt load issued before
//    softmax (latency hidden under VALU); setprio(1) around PV MFMAs.

#define SEQ 577
#define DMODEL 768
#define NHEADS 12
#define HDIM 64
#define MTOTAL (32 * SEQ)      /* 18464 */
#define MPAD 18560             /* 145*128 */
#define KP 608                 /* padded key count */
#define STW 616                /* St row stride in shorts; 1232 B */
#define NKSTEP (DMODEL / 64)   /* 12 */

typedef __attribute__((ext_vector_type(8))) short bf16x8;
typedef __attribute__((ext_vector_type(4))) float f32x4;

#define MFMA_BF16(a, b, c) __builtin_amdgcn_mfma_f32_16x16x32_bf16((a), (b), (c), 0, 0, 0)

static __device__ __forceinline__ unsigned short f2bf(float x) {
    unsigned int u = __float_as_uint(x);
    return (unsigned short)((u + 0x7FFFu + ((u >> 16) & 1u)) >> 16);
}
static __device__ __forceinline__ float bf2f(unsigned short s) {
    return __uint_as_float((unsigned int)s << 16);
}
static __device__ __forceinline__ void cvt8(unsigned short* dst, const float* src) {
    float4 a = *reinterpret_cast<const float4*>(src);
    float4 b = *reinterpret_cast<const float4*>(src + 4);
    union { unsigned short us[8]; int4 v; } u;
    u.us[0] = f2bf(a.x); u.us[1] = f2bf(a.y); u.us[2] = f2bf(a.z); u.us[3] = f2bf(a.w);
    u.us[4] = f2bf(b.x); u.us[5] = f2bf(b.y); u.us[6] = f2bf(b.z); u.us[7] = f2bf(b.w);
    *reinterpret_cast<int4*>(dst) = u.v;
}
static __device__ __forceinline__ void gload_lds16(const void* g, void* l) {
    __builtin_amdgcn_global_load_lds(
        (const __attribute__((address_space(1))) void*)g,
        (__attribute__((address_space(3))) void*)l, 16, 0, 0);
}

// ---------------------------------------------------------------------------
// fp32 -> bf16 convert pass (FAST path only).
// ---------------------------------------------------------------------------
#define NX8 (MTOTAL * DMODEL / 8)
#define NW8 (DMODEL * DMODEL / 8)
__global__ __launch_bounds__(256) void conv_kernel(
    const float* __restrict__ X, const float* __restrict__ Wq,
    const float* __restrict__ Wk, const float* __restrict__ Wv,
    unsigned short* __restrict__ Xb, unsigned short* __restrict__ Wb)
{
    const int total = NX8 + 3 * NW8;
    for (int i = blockIdx.x * blockDim.x + threadIdx.x; i < total;
         i += gridDim.x * blockDim.x) {
        if (i < NX8) {
            cvt8(Xb + (size_t)i * 8, X + (size_t)i * 8);
        } else {
            int j = i - NX8;
            int w = j / NW8, o = j - w * NW8;
            const float* Wf = (w == 0) ? Wq : ((w == 1) ? Wk : Wv);
            cvt8(Wb + (size_t)w * DMODEL * DMODEL + (size_t)o * 8, Wf + (size_t)o * 8);
        }
    }
}

// ---------------------------------------------------------------------------
// QKV GEMM: C[m,n] = X[m,:] . W[n,:] + b[n], 128x128 tile, 4 waves (2x2), BK=64.
// FAST: dbuf LDS + counted vmcnt + XOR swizzle (linear LDS, pre-swizzled src).
// ---------------------------------------------------------------------------
template<bool FAST>
__global__ __launch_bounds__(256) void gemm_qkv(
    const float* __restrict__ X, const unsigned short* __restrict__ Xb,
    const float* __restrict__ Wq, const float* __restrict__ Wk,
    const float* __restrict__ Wv, const unsigned short* __restrict__ Wb,
    const float* __restrict__ bq, const float* __restrict__ bk,
    const float* __restrict__ bv,
    unsigned short* __restrict__ Qb, unsigned short* __restrict__ Kb,
    unsigned short* __restrict__ Vt, int vstride)
{
    __shared__ __align__(16) unsigned short As[FAST ? 2 * 128 * 64 : 128 * 72];
    __shared__ __align__(16) unsigned short Bs[FAST ? 2 * 128 * 64 : 128 * 72];

    const int z = blockIdx.z;
    const float* bias = (z == 0) ? bq : ((z == 1) ? bk : bv);
    const float outscale = (z == 0) ? 0.125f : 1.0f;

    const int m0 = blockIdx.x * 128;
    const int n0 = blockIdx.y * 128;
    const int t = (int)threadIdx.x;
    const int lane = t & 63, wid = t >> 6;
    const int hi = lane >> 4, l15 = lane & 15;
    const int wr = wid >> 1, wc = wid & 1;

    const f32x4 zero = {0.f, 0.f, 0.f, 0.f};
    f32x4 acc[4][4];
    #pragma unroll
    for (int i = 0; i < 4; ++i)
        #pragma unroll
        for (int j = 0; j < 4; ++j) acc[i][j] = zero;

    if constexpr (FAST) {
        // staging: wave w stages rows {8w..8w+7}+32c; lane's global column is
        // pre-swizzled so that (linear LDS dest) == swizzled layout.
        const int srow = wid * 8 + (lane >> 3);
        const int scol = (((lane & 7) ^ ((lane >> 3) & 7))) * 8;
        const unsigned short* gA = Xb + (size_t)(m0 + srow) * DMODEL + scol;
        const unsigned short* gB = Wb + (size_t)z * DMODEL * DMODEL
                                      + (size_t)(n0 + srow) * DMODEL + scol;
        #define STAGE(buf, k0)                                                     \
            {                                                                      \
                _Pragma("unroll")                                                  \
                for (int c = 0; c < 4; ++c) {                                      \
                    gload_lds16(gA + (size_t)c * 32 * DMODEL + (k0),               \
                                &As[(buf) * 8192 + wid * 512 + c * 2048]);         \
                    gload_lds16(gB + (size_t)c * 32 * DMODEL + (k0),               \
                                &Bs[(buf) * 8192 + wid * 512 + c * 2048]);         \
                }                                                                  \
            }
        STAGE(0, 0);
        int cur = 0;
        for (int kt = 0; kt < NKSTEP; ++kt) {
            if (kt + 1 < NKSTEP) {
                STAGE(cur ^ 1, (kt + 1) * 64);
                asm volatile("s_waitcnt vmcnt(8)" ::: "memory");
            } else {
                asm volatile("s_waitcnt vmcnt(0)" ::: "memory");
            }
            __builtin_amdgcn_s_barrier(); // this tile staged, all waves
            #pragma unroll
            for (int kc = 0; kc < 2; ++kc) {
                const int pc = ((kc * 4 + hi) ^ (l15 & 7)) * 8; // swizzled chunk
                bf16x8 a[4], b[4];
                #pragma unroll
                for (int i = 0; i < 4; ++i)
                    a[i] = *reinterpret_cast<const bf16x8*>(
                        &As[cur * 8192 + (wr * 64 + i * 16 + l15) * 64 + pc]);
                #pragma unroll
                for (int i = 0; i < 4; ++i)
                    b[i] = *reinterpret_cast<const bf16x8*>(
                        &Bs[cur * 8192 + (wc * 64 + i * 16 + l15) * 64 + pc]);
                #pragma unroll
                for (int mf = 0; mf < 4; ++mf)
                    #pragma unroll
                    for (int nf = 0; nf < 4; ++nf)
                        acc[mf][nf] = MFMA_BF16(a[mf], b[nf], acc[mf][nf]);
            }
            __builtin_amdgcn_s_barrier(); // done reading before overwrite
            cur ^= 1;
        }
        #undef STAGE
    } else {
        const int lrow = t >> 1, lcol = (t & 1) * 32;
        int xr = m0 + lrow; if (xr > MTOTAL - 1) xr = MTOTAL - 1;
        const float* xp = X + (size_t)xr * DMODEL + lcol;
        const float* Wf = (z == 0) ? Wq : ((z == 1) ? Wk : Wv);
        const float* wp = Wf + (size_t)(n0 + lrow) * DMODEL + lcol;
        for (int k0 = 0; k0 < DMODEL; k0 += 64) {
            #pragma unroll
            for (int c = 0; c < 4; ++c) {
                cvt8(&As[lrow * 72 + lcol + c * 8], xp + k0 + c * 8);
                cvt8(&Bs[lrow * 72 + lcol + c * 8], wp + k0 + c * 8);
            }
            __syncthreads();
            #pragma unroll
            for (int kc = 0; kc < 2; ++kc) {
                bf16x8 a[4], b[4];
                #pragma unroll
                for (int i = 0; i < 4; ++i)
                    a[i] = *reinterpret_cast<const bf16x8*>(
                        &As[(wr * 64 + i * 16 + l15) * 72 + kc * 32 + hi * 8]);
                #pragma unroll
                for (int i = 0; i < 4; ++i)
                    b[i] = *reinterpret_cast<const bf16x8*>(
                        &Bs[(wc * 64 + i * 16 + l15) * 72 + kc * 32 + hi * 8]);
                #pragma unroll
                for (int mf = 0; mf < 4; ++mf)
                    #pragma unroll
                    for (int nf = 0; nf < 4; ++nf)
                        acc[mf][nf] = MFMA_BF16(a[mf], b[nf], acc[mf][nf]);
            }
            __syncthreads();
        }
    }

    // epilogue
    #pragma unroll
    for (int nf = 0; nf < 4; ++nf) {
        const int n = n0 + wc * 64 + nf * 16 + l15;
        const float bval = bias[n];
        const int h = n >> 6, dd = n & 63;
        #pragma unroll
        for (int mf = 0; mf < 4; ++mf) {
            #pragma unroll
            for (int r = 0; r < 4; ++r) {
                const int gm = m0 + wr * 64 + mf * 16 + hi * 4 + r;
                if (gm < MTOTAL) {
                    const int bi = gm / SEQ, s = gm - ((gm / SEQ) * SEQ);
                    const int bh = bi * NHEADS + h;
                    const unsigned short v = f2bf((acc[mf][nf][r] + bval) * outscale);
                    if (z == 2)
                        Vt[((size_t)bh * HDIM + dd) * vstride + s] = v;
                    else if (z == 0)
                        Qb[((size_t)bh * SEQ + s) * HDIM + dd] = v;
                    else
                        Kb[((size_t)bh * SEQ + s) * HDIM + dd] = v;
                }
            }
        }
    }
}

// ---------------------------------------------------------------------------
// Fused attention v2: block = (32 q-rows, bh), 4 waves, 39.6KB LDS -> 4 blk/CU.
// St[q][key] bf16, stride 1232 B (bank-balanced). K/Vt loads register-prefetched.
// ---------------------------------------------------------------------------
__global__ __launch_bounds__(256) void attn2(
    const unsigned short* __restrict__ Qb,
    const unsigned short* __restrict__ Kb,
    const unsigned short* __restrict__ Vt,
    float* __restrict__ Out, int vstride)
{
    __shared__ __align__(16) unsigned short St[32 * STW]; // 39424 B
    __shared__ float rowinv[32];

    const int qt = blockIdx.x, bh = blockIdx.y;
    const int s0 = qt * 32;
    const int t = (int)threadIdx.x;
    const int lane = t & 63, wid = t >> 6;
    const int hi = lane >> 4, l15 = lane & 15;
    const size_t base = (size_t)bh * SEQ * HDIM;
    const f32x4 zero = {0.f, 0.f, 0.f, 0.f};

    // --- Q B-frags from global (clamped rows)
    bf16x8 qf0[2], qf1[2];
    #pragma unroll
    for (int mb = 0; mb < 2; ++mb) {
        int qrow = s0 + mb * 16 + l15; if (qrow > SEQ - 1) qrow = SEQ - 1;
        const unsigned short* qp = Qb + base + (size_t)qrow * HDIM + hi * 8;
        qf0[mb] = *reinterpret_cast<const bf16x8*>(qp);
        qf1[mb] = *reinterpret_cast<const bf16x8*>(qp + 32);
    }

    // --- swapped QK^T with 1-deep K prefetch
    bf16x8 kb0, kb1;
    {
        int kr = wid * 16 + l15; if (kr > SEQ - 1) kr = SEQ - 1;
        const unsigned short* kp = Kb + base + (size_t)kr * HDIM + hi * 8;
        kb0 = *reinterpret_cast<const bf16x8*>(kp);
        kb1 = *reinterpret_cast<const bf16x8*>(kp + 32);
    }
    for (int kt = wid; kt < 37; kt += 4) {
        bf16x8 nb0 = kb0, nb1 = kb1;
        if (kt + 4 < 37) {
            int kr = (kt + 4) * 16 + l15; if (kr > SEQ - 1) kr = SEQ - 1;
            const unsigned short* kp = Kb + base + (size_t)kr * HDIM + hi * 8;
            nb0 = *reinterpret_cast<const bf16x8*>(kp);
            nb1 = *reinterpret_cast<const bf16x8*>(kp + 32);
        }
        f32x4 acc0 = zero, acc1 = zero;
        acc0 = MFMA_BF16(kb0, qf0[0], acc0);
        acc0 = MFMA_BF16(kb1, qf1[0], acc0);
        acc1 = MFMA_BF16(kb0, qf0[1], acc1);
        acc1 = MFMA_BF16(kb1, qf1[1], acc1);
        const int obase = 32 * kt + 8 * hi;
        {
            char* rowp = (char*)St + l15 * (STW * 2);
            int2 w = {(int)((unsigned int)f2bf(acc0[0]) | ((unsigned int)f2bf(acc0[1]) << 16)),
                      (int)((unsigned int)f2bf(acc0[2]) | ((unsigned int)f2bf(acc0[3]) << 16))};
            *reinterpret_cast<int2*>(rowp + obase) = w;
        }
        {
            char* rowp = (char*)St + (16 + l15) * (STW * 2);
            int2 w = {(int)((unsigned int)f2bf(acc1[0]) | ((unsigned int)f2bf(acc1[1]) << 16)),
                      (int)((unsigned int)f2bf(acc1[2]) | ((unsigned int)f2bf(acc1[3]) << 16))};
            *reinterpret_cast<int2*>(rowp + obase) = w;
        }
        kb0 = nb0; kb1 = nb1;
    }
    __syncthreads();

    // --- issue first PV V-load early (hidden under softmax VALU)
    const int dd = wid * 16 + l15;
    const unsigned short* vbase = Vt + ((size_t)bh * HDIM + dd) * vstride;
    bf16x8 vcur;
    {
        int vk = hi * 8; if (vk > 576) vk = 576;
        union { bf16x8 v8; int2 d2[2]; } u;
        u.d2[0] = *reinterpret_cast<const int2*>(vbase + vk);
        u.d2[1] = *reinterpret_cast<const int2*>(vbase + vk + 4);
        vcur = u.v8;
    }

    // --- softmax: 8 threads/row, vectorized; P (unnormalized bf16) in place
    {
        const int r = t >> 3, j = t & 7;
        char* rowp = (char*)St + r * (STW * 2);
        float mx = -1e30f;
        for (int cc = j; cc < 74; cc += 8) {
            bf16x8 v = *reinterpret_cast<const bf16x8*>(rowp + cc * 16);
            #pragma unroll
            for (int e = 0; e < 8; ++e) mx = fmaxf(mx, bf2f((unsigned short)v[e]));
        }
        mx = fmaxf(mx, __shfl_xor(mx, 1));
        mx = fmaxf(mx, __shfl_xor(mx, 2));
        mx = fmaxf(mx, __shfl_xor(mx, 4));
        float sum = 0.f;
        for (int cc = j; cc < 74; cc += 8) {
            bf16x8 v = *reinterpret_cast<const bf16x8*>(rowp + cc * 16);
            unsigned int w[4];
            #pragma unroll
            for (int e = 0; e < 8; e += 2) {
                float p0 = __expf(bf2f((unsigned short)v[e]) - mx);
                float p1 = __expf(bf2f((unsigned short)v[e + 1]) - mx);
                if (cc * 8 + e     >= SEQ) p0 = 0.f;
                if (cc * 8 + e + 1 >= SEQ) p1 = 0.f;
                sum += p0 + p1;
                w[e >> 1] = (unsigned int)f2bf(p0) | ((unsigned int)f2bf(p1) << 16);
            }
            int4 wv = {(int)w[0], (int)w[1], (int)w[2], (int)w[3]};
            *reinterpret_cast<int4*>(rowp + cc * 16) = wv;
        }
        if (j < 2) {
            int4 zv = {0, 0, 0, 0};
            *reinterpret_cast<int4*>(rowp + (74 + j) * 16) = zv;
        }
        sum += __shfl_xor(sum, 1);
        sum += __shfl_xor(sum, 2);
        sum += __shfl_xor(sum, 4);
        if (j == 0) rowinv[r] = 1.0f / sum;
    }
    __syncthreads();

    // --- PV with 1-deep Vt prefetch; setprio around MFMA
    f32x4 o0 = zero, o1 = zero;
    __builtin_amdgcn_s_setprio(1);
    for (int k0 = 0; k0 < KP; k0 += 32) {
        bf16x8 vnext = vcur;
        if (k0 + 32 < KP) {
            int vk = k0 + 32 + hi * 8; if (vk > 576) vk = 576;
            union { bf16x8 v8; int2 d2[2]; } u;
            u.d2[0] = *reinterpret_cast<const int2*>(vbase + vk);
            u.d2[1] = *reinterpret_cast<const int2*>(vbase + vk + 4);
            vnext = u.v8;
        }
        const char* pbase = (const char*)St + 2 * k0 + 16 * hi;
        bf16x8 pa0 = *reinterpret_cast<const bf16x8*>(pbase + l15 * (STW * 2));
        bf16x8 pa1 = *reinterpret_cast<const bf16x8*>(pbase + (16 + l15) * (STW * 2));
        o0 = MFMA_BF16(pa0, vcur, o0);
        o1 = MFMA_BF16(pa1, vcur, o1);
        vcur = vnext;
    }
    __builtin_amdgcn_s_setprio(0);

    // --- store
    const int bi = bh / NHEADS, h = bh - bi * NHEADS;
    #pragma unroll
    for (int r = 0; r < 4; ++r) {
        {
            const int q = hi * 4 + r, s = s0 + q;
            if (s < SEQ)
                Out[((size_t)bi * SEQ + s) * DMODEL + h * HDIM + dd] = o0[r] * rowinv[q];
        }
        {
            const int q = 16 + hi * 4 + r, s = s0 + q;
            if (s < SEQ)
                Out[((size_t)bi * SEQ + s) * DMODEL + h * HDIM + dd] = o1[r] * rowinv[q];
        }
    }
}

extern "C" void kernel_launch(void* const* d_in, const int* in_sizes, int n_in,
                              void* d_out, int out_size, void* d_ws, size_t ws_size,
                              hipStream_t stream) {
    (void)in_sizes; (void)n_in; (void)out_size;
    const float* X  = (const float*)d_in[0];
    const float* Wq = (const float*)d_in[1];
    const float* bq = (const float*)d_in[2];
    const float* Wk = (const float*)d_in[3];
    const float* bk = (const float*)d_in[4];
    const float* Wv = (const float*)d_in[5];
    const float* bv = (const float*)d_in[6];
    float* Out = (float*)d_out;

    const size_t E_QK = (size_t)MTOTAL * DMODEL;
    const size_t E_XB = (size_t)MPAD * DMODEL;
    const size_t E_WB = 3ull * DMODEL * DMODEL;
    const size_t E_VT_F = 384ull * HDIM * KP;
    const size_t need_fast = (E_XB + E_WB + 2 * E_QK + E_VT_F) * 2;

    const bool fast = (ws_size >= need_fast);
    unsigned short* p = (unsigned short*)d_ws;
    unsigned short *Xb = nullptr, *Wb = nullptr, *Qb, *Kb, *Vt;
    int vstride;
    if (fast) {
        Xb = p; p += E_XB;
        Wb = p; p += E_WB;
        Qb = p; p += E_QK;
        Kb = p; p += E_QK;
        Vt = p;
        vstride = KP;
    } else {
        Qb = p; p += E_QK;
        Kb = p; p += E_QK;
        Vt = p;
        vstride = 584;
    }

    dim3 gg((MPAD) / 128, DMODEL / 128, 3);
    if (fast) {
        conv_kernel<<<2048, 256, 0, stream>>>(X, Wq, Wk, Wv, Xb, Wb);
        gemm_qkv<true><<<gg, 256, 0, stream>>>(X, Xb, Wq, Wk, Wv, Wb,
                                               bq, bk, bv, Qb, Kb, Vt, vstride);
    } else {
        gemm_qkv<false><<<gg, 256, 0, stream>>>(X, Xb, Wq, Wk, Wv, Wb,
                                                bq, bk, bv, Qb, Kb, Vt, vstride);
    }
    attn2<<<dim3((SEQ + 31) / 32, 32 * NHEADS), 256, 0, stream>>>(Qb, Kb, Vt, Out, vstride);
}